// Round 4
// baseline (453.268 us; speedup 1.0000x reference)
//
#include <hip/hip_runtime.h>
#include <hip/hip_bf16.h>

typedef __hip_bfloat16 bf16;
__device__ __forceinline__ float bf2f(bf16 v) { return __bfloat162float(v); }

typedef __attribute__((ext_vector_type(8))) short short8;
typedef __attribute__((ext_vector_type(4))) float floatx4;

// ===========================================================================
// Strategy (round 3): NO sort / NO perm. Two scatter-add phases with
// fire-and-forget global_atomic_add_f32 into f32 accumulators that were
// zeroed in-kernel right before (so lines are at the coherence point; no
// HBM write-allocate like round-2's scattered perm stores, which hit 128MB
// WRITE_SIZE). Atomics need no return -> no latency stall, issue-bound.
//   Xe[e]   += Xl[v]                  (e-scatter, 64 lanes = 64 features)
//   accV[v] += (degE[e]*W_edge[e]) * Xe[e]   (v-scatter, scale folded in)
//   out[v]   = accV[v] * degV[v]      (finalize)
// ===========================================================================

__global__ __launch_bounds__(256) void zero_kernel(float* __restrict__ buf, int n4) {
  const float4 z = {0.f, 0.f, 0.f, 0.f};
  for (int i = blockIdx.x * 256 + threadIdx.x; i < n4; i += gridDim.x * 256)
    ((float4*)buf)[i] = z;
}

// ---------------------------------------------------------------------------
// e-scatter: one wave per 64 incidences. lane = feature. For each incidence
// j: all lanes read Xl[v_j][lane] (bf16, 128B/wave, L2/L3-hit) and
// atomicAdd into Xe[e_j][lane] (f32). No return used -> pipelined.
// ---------------------------------------------------------------------------
__global__ __launch_bounds__(256) void escatter_kernel(
    const bf16* __restrict__ Xl, const int* __restrict__ vertex,
    const int* __restrict__ edges, float* __restrict__ Xe, int nnz) {
  const int wave = blockIdx.x * 4 + (threadIdx.x >> 6);
  const int lane = threadIdx.x & 63;
  const int base = wave * 64;
  if (base >= nnz) return;
  const int n = min(64, nnz - base);

  const int v = (lane < n) ? vertex[base + lane] : 0;
  const int e = (lane < n) ? edges[base + lane] : 0;

  if (n == 64) {
#pragma unroll
    for (int j = 0; j < 64; j += 4) {
      const int v0 = __shfl(v, j + 0, 64), e0 = __shfl(e, j + 0, 64);
      const int v1 = __shfl(v, j + 1, 64), e1 = __shfl(e, j + 1, 64);
      const int v2 = __shfl(v, j + 2, 64), e2 = __shfl(e, j + 2, 64);
      const int v3 = __shfl(v, j + 3, 64), e3 = __shfl(e, j + 3, 64);
      const float f0 = bf2f(Xl[(size_t)v0 * 64 + lane]);
      const float f1 = bf2f(Xl[(size_t)v1 * 64 + lane]);
      const float f2 = bf2f(Xl[(size_t)v2 * 64 + lane]);
      const float f3 = bf2f(Xl[(size_t)v3 * 64 + lane]);
      atomicAdd(&Xe[(size_t)e0 * 64 + lane], f0);
      atomicAdd(&Xe[(size_t)e1 * 64 + lane], f1);
      atomicAdd(&Xe[(size_t)e2 * 64 + lane], f2);
      atomicAdd(&Xe[(size_t)e3 * 64 + lane], f3);
    }
  } else {
    for (int j = 0; j < n; ++j) {
      const int vj = __shfl(v, j, 64), ej = __shfl(e, j, 64);
      const float f = bf2f(Xl[(size_t)vj * 64 + lane]);
      atomicAdd(&Xe[(size_t)ej * 64 + lane], f);
    }
  }
}

// ---------------------------------------------------------------------------
// v-scatter: accV[v] += sE[e] * Xe[e], sE = degE*W_edge (per-lane preload,
// shfl-broadcast). Xe reads are f32 (256B/wave) from L2/L3.
// ---------------------------------------------------------------------------
__global__ __launch_bounds__(256) void vscatter_kernel(
    const float* __restrict__ Xe, const int* __restrict__ vertex,
    const int* __restrict__ edges, const float* __restrict__ degE,
    const float* __restrict__ W_edge, float* __restrict__ accV, int nnz) {
  const int wave = blockIdx.x * 4 + (threadIdx.x >> 6);
  const int lane = threadIdx.x & 63;
  const int base = wave * 64;
  if (base >= nnz) return;
  const int n = min(64, nnz - base);

  const int v   = (lane < n) ? vertex[base + lane] : 0;
  const int e   = (lane < n) ? edges[base + lane] : 0;
  const float s = (lane < n) ? degE[e] * W_edge[e] : 0.f;

  if (n == 64) {
#pragma unroll
    for (int j = 0; j < 64; j += 4) {
      const int v0 = __shfl(v, j + 0, 64), e0 = __shfl(e, j + 0, 64);
      const int v1 = __shfl(v, j + 1, 64), e1 = __shfl(e, j + 1, 64);
      const int v2 = __shfl(v, j + 2, 64), e2 = __shfl(e, j + 2, 64);
      const int v3 = __shfl(v, j + 3, 64), e3 = __shfl(e, j + 3, 64);
      const float s0 = __shfl(s, j + 0, 64), s1 = __shfl(s, j + 1, 64);
      const float s2 = __shfl(s, j + 2, 64), s3 = __shfl(s, j + 3, 64);
      const float f0 = Xe[(size_t)e0 * 64 + lane] * s0;
      const float f1 = Xe[(size_t)e1 * 64 + lane] * s1;
      const float f2 = Xe[(size_t)e2 * 64 + lane] * s2;
      const float f3 = Xe[(size_t)e3 * 64 + lane] * s3;
      atomicAdd(&accV[(size_t)v0 * 64 + lane], f0);
      atomicAdd(&accV[(size_t)v1 * 64 + lane], f1);
      atomicAdd(&accV[(size_t)v2 * 64 + lane], f2);
      atomicAdd(&accV[(size_t)v3 * 64 + lane], f3);
    }
  } else {
    for (int j = 0; j < n; ++j) {
      const int vj = __shfl(v, j, 64), ej = __shfl(e, j, 64);
      const float sj = __shfl(s, j, 64);
      const float f = Xe[(size_t)ej * 64 + lane] * sj;
      atomicAdd(&accV[(size_t)vj * 64 + lane], f);
    }
  }
}

// ---------------------------------------------------------------------------
// finalize: out[v][c] = accV[v][c] * degV[v]; floatx4 (clang ext-vector —
// __builtin_nontemporal_store rejects HIP_vector_type float4).
// ---------------------------------------------------------------------------
__global__ __launch_bounds__(256) void finalize_kernel(
    const float* __restrict__ accV, const float* __restrict__ degV,
    float* __restrict__ out, int N) {
  const int total4 = N * 16;   // 64 floats per row = 16 float4
  for (int i = blockIdx.x * 256 + threadIdx.x; i < total4; i += gridDim.x * 256) {
    floatx4 a = ((const floatx4*)accV)[i];
    const float d = degV[i >> 4];
    a *= d;
    __builtin_nontemporal_store(a, &((floatx4*)out)[i]);
  }
}

// ===========================================================================
// MFMA GEMM: Xl[N,64] (bf16) = X[N,128] (f32) @ W[128,64] (f32).
// Block = 4 waves; 64-row tile x 64 cols; K=128 via mfma_f32_16x16x32_bf16.
// (unchanged from round 1)
// ===========================================================================
__device__ __forceinline__ unsigned int pack_bf16x2(float lo, float hi) {
  bf16 a = __float2bfloat16(lo);
  bf16 b = __float2bfloat16(hi);
  unsigned short ua = *(unsigned short*)&a;
  unsigned short ub = *(unsigned short*)&b;
  return (unsigned int)ua | ((unsigned int)ub << 16);
}

#define XS_STRIDE 136   // ushort; 16B-aligned rows, 2-way-free fragment reads

__global__ __launch_bounds__(256) void gemm_kernel(
    const float* __restrict__ X, const float* __restrict__ W,
    bf16* __restrict__ Xl, int Nrows, int ntiles) {
  __shared__ unsigned short Ws[64 * XS_STRIDE];   // W^T: [n][k] bf16, 17.4 KB
  __shared__ unsigned short Xs[64 * XS_STRIDE];   // [m][k] bf16,     17.4 KB

  const int tid  = threadIdx.x;
  const int wave = tid >> 6;
  const int lane = tid & 63;
  const int quad = lane >> 4;
  const int l15  = lane & 15;

  for (int i = tid; i < 8192; i += 256) {
    const int k = i >> 6, n = i & 63;
    bf16 h = __float2bfloat16(W[i]);
    Ws[n * XS_STRIDE + k] = *(unsigned short*)&h;
  }
  __syncthreads();

  short8 bfrag[4][4];
#pragma unroll
  for (int ct = 0; ct < 4; ++ct)
#pragma unroll
    for (int kt = 0; kt < 4; ++kt)
      bfrag[ct][kt] = *(const short8*)&Ws[(ct * 16 + l15) * XS_STRIDE + kt * 32 + quad * 8];

  const int r  = tid >> 2;
  const int c0 = (tid & 3) * 32;

  for (int tile = blockIdx.x; tile < ntiles; tile += gridDim.x) {
    const int row0 = tile * 64;
    {
      int rr = row0 + r;
      if (rr >= Nrows) rr = Nrows - 1;
      const float* src = X + (size_t)rr * 128 + c0;
      unsigned short* dst = &Xs[r * XS_STRIDE + c0];
#pragma unroll
      for (int q = 0; q < 4; ++q) {
        const float4 f0 = *(const float4*)(src + q * 8);
        const float4 f1 = *(const float4*)(src + q * 8 + 4);
        uint4 o;
        o.x = pack_bf16x2(f0.x, f0.y);
        o.y = pack_bf16x2(f0.z, f0.w);
        o.z = pack_bf16x2(f1.x, f1.y);
        o.w = pack_bf16x2(f1.z, f1.w);
        *(uint4*)(dst + q * 8) = o;
      }
    }
    __syncthreads();

    const int m = wave * 16 + l15;
    short8 afrag[4];
#pragma unroll
    for (int kt = 0; kt < 4; ++kt)
      afrag[kt] = *(const short8*)&Xs[m * XS_STRIDE + kt * 32 + quad * 8];

    floatx4 acc[4];
#pragma unroll
    for (int ct = 0; ct < 4; ++ct) {
      acc[ct] = (floatx4){0.f, 0.f, 0.f, 0.f};
#pragma unroll
      for (int kt = 0; kt < 4; ++kt)
        acc[ct] = __builtin_amdgcn_mfma_f32_16x16x32_bf16(
            afrag[kt], bfrag[ct][kt], acc[ct], 0, 0, 0);
    }

    const int rbase_ = row0 + wave * 16 + quad * 4;
#pragma unroll
    for (int ct = 0; ct < 4; ++ct) {
      const int col = ct * 16 + l15;
#pragma unroll
      for (int reg = 0; reg < 4; ++reg) {
        const int row = rbase_ + reg;
        if (row < Nrows) Xl[(size_t)row * 64 + col] = __float2bfloat16(acc[ct][reg]);
      }
    }
    __syncthreads();
  }
}

// ===========================================================================
extern "C" void kernel_launch(void* const* d_in, const int* in_sizes, int n_in,
                              void* d_out, int out_size, void* d_ws, size_t ws_size,
                              hipStream_t stream) {
  const float* X      = (const float*)d_in[0];
  const int*   vertex = (const int*)d_in[1];
  const int*   edges  = (const int*)d_in[2];
  const float* W      = (const float*)d_in[3];
  const float* degE   = (const float*)d_in[4];
  const float* degV   = (const float*)d_in[5];
  const float* W_edge = (const float*)d_in[6];
  float* out = (float*)d_out;

  const int nnz = in_sizes[1];
  const int E   = in_sizes[4];
  const int N   = in_sizes[5];

  char* p = (char*)d_ws;
  auto alloc = [&](size_t bytes) -> void* {
    void* r = (void*)p;
    p += (bytes + 255) & ~(size_t)255;
    return r;
  };
  // Xe and accV adjacent -> zeroed in one pass.
  float* Xe   = (float*)alloc((size_t)E * 64 * 4);   //  5.1 MB f32
  float* accV = (float*)alloc((size_t)N * 64 * 4);   // 25.6 MB f32
  bf16*  Xl   = (bf16*)alloc((size_t)N * 64 * 2);    // 12.8 MB

  const int zero4   = (E + N) * 16;                  // float4 count (contiguous)
  const int zblocks = min((zero4 + 255) / 256, 2048);
  const int sblocks = ((nnz + 63) / 64 + 3) / 4;     // waves of 64 incidences
  const int ntiles  = (N + 63) / 64;
  const int gblocks = ntiles < 512 ? ntiles : 512;
  const int fblocks = min((N * 16 + 255) / 256, 2048);

  zero_kernel<<<zblocks, 256, 0, stream>>>(Xe, zero4);
  gemm_kernel<<<gblocks, 256, 0, stream>>>(X, W, Xl, N, ntiles);
  escatter_kernel<<<sblocks, 256, 0, stream>>>(Xl, vertex, edges, Xe, nnz);
  vscatter_kernel<<<sblocks, 256, 0, stream>>>(Xe, vertex, edges, degE, W_edge, accV, nnz);
  finalize_kernel<<<fblocks, 256, 0, stream>>>(accV, degV, out, N);
}